// Round 1
// baseline (459.184 us; speedup 1.0000x reference)
//
#include <hip/hip_runtime.h>
#include <cstdint>
#include <cstddef>

// Problem: B=4, S=4096, HID=1024, H=16, DH=64
//   qkv = query @ W^T + b    (M=16384, N=3072, K=1024)
//   per-position (b,s): scores = q(16x64) @ k^T /8 + mask(16x16); softmax; o = p @ v(16x64)
// Pipeline: cast fp32->bf16 (query, W) -> MFMA GEMM (bf16, fp32 acc, +bias, store bf16)
//           -> per-position attention in fp32 -> out fp32.
// ws layout: Qb bf16 [16M el] @0 ; Wb bf16 [3M el] @33554432 ; QKVb bf16 [48M el] @39845888
//   total 140,509,184 bytes.

typedef __attribute__((ext_vector_type(8))) short bf16x8;
typedef __attribute__((ext_vector_type(4))) float f32x4;

__device__ inline float bf2f(unsigned short u) {
  union { unsigned int i; float f; } x; x.i = ((unsigned int)u) << 16; return x.f;
}
__device__ inline unsigned short f2bf(float f) {
  unsigned int i = __float_as_uint(f);
  i += 0x7fff + ((i >> 16) & 1);   // RNE
  return (unsigned short)(i >> 16);
}

__device__ inline void async16(const void* g, void* l) {
  __builtin_amdgcn_global_load_lds(
      (const __attribute__((address_space(1))) void*)g,
      (__attribute__((address_space(3))) void*)l, 16, 0, 0);
}

// ---------------- cast fp32 -> bf16, 4 elems/thread ----------------
__global__ __launch_bounds__(256) void cast_kernel(const float* __restrict__ in,
                                                   unsigned short* __restrict__ out,
                                                   int n) {
  int i = (blockIdx.x * 256 + threadIdx.x) * 4;
  if (i >= n) return;
  float4 v = *(const float4*)(in + i);
  union { unsigned short u[4]; unsigned long long ll; } o;
  o.u[0] = f2bf(v.x); o.u[1] = f2bf(v.y); o.u[2] = f2bf(v.z); o.u[3] = f2bf(v.w);
  *(unsigned long long*)(out + i) = o.ll;
}

// ---------------- GEMM: C[M=16384][N=3072] = A[M][1024] * B[N][1024]^T + bias ----------------
// 128x128 tile, BK=64, 256 threads (4 waves, 2x2 of 64x64), mfma 16x16x32 bf16.
#define GK 1024
#define GN 3072
__global__ __launch_bounds__(256) void gemm_qkv(const unsigned short* __restrict__ A,
                                                const unsigned short* __restrict__ Bm,
                                                const float* __restrict__ bias,
                                                unsigned short* __restrict__ C) {
  __shared__ unsigned short As[128 * 64];
  __shared__ unsigned short Bs[128 * 64];
  const int m0 = blockIdx.x * 128;
  const int n0 = blockIdx.y * 128;
  const int tid  = threadIdx.x;
  const int lane = tid & 63;
  const int wave = tid >> 6;
  const int wm = wave & 1, wn = wave >> 1;       // 2x2 waves, each 64x64
  const int fr = lane & 15;                      // m (A) / n (B) within 16
  const int fq = lane >> 4;                      // quad -> k offset fq*8

  f32x4 acc[4][4] = {};

  for (int k0 = 0; k0 < GK; k0 += 64) {
    // stage A,B tiles: 1024 16B-chunks each; wave-uniform LDS base + lane*16
    #pragma unroll
    for (int t = 0; t < 4; ++t) {
      int sbase = t * 256 + wave * 64;           // wave-uniform slot base
      int sl = sbase + lane;
      int r = sl >> 3;
      int c = (sl & 7) * 8;
      async16(&A[(size_t)(m0 + r) * GK + k0 + c], &As[sbase * 8]);
      async16(&Bm[(size_t)(n0 + r) * GK + k0 + c], &Bs[sbase * 8]);
    }
    __syncthreads();
    #pragma unroll
    for (int ks = 0; ks < 64; ks += 32) {
      bf16x8 af[4], bf[4];
      #pragma unroll
      for (int i = 0; i < 4; ++i) {
        int arow = wm * 64 + i * 16 + fr;
        af[i] = *(const bf16x8*)&As[arow * 64 + ks + fq * 8];
        int brow = wn * 64 + i * 16 + fr;
        bf[i] = *(const bf16x8*)&Bs[brow * 64 + ks + fq * 8];
      }
      #pragma unroll
      for (int i = 0; i < 4; ++i)
        #pragma unroll
        for (int j = 0; j < 4; ++j)
          acc[i][j] = __builtin_amdgcn_mfma_f32_16x16x32_bf16(af[i], bf[j], acc[i][j], 0, 0, 0);
    }
    __syncthreads();
  }

  // epilogue: C[row][col] = acc + bias[col], store bf16
  #pragma unroll
  for (int i = 0; i < 4; ++i) {
    #pragma unroll
    for (int j = 0; j < 4; ++j) {
      int col = n0 + wn * 64 + j * 16 + fr;
      float bc = bias[col];
      #pragma unroll
      for (int r = 0; r < 4; ++r) {
        int row = m0 + wm * 64 + i * 16 + fq * 4 + r;
        C[(size_t)row * GN + col] = f2bf(acc[i][j][r] + bc);
      }
    }
  }
}

// ---------------- per-position attention ----------------
// one wave per position; lane l: h = l&15, dgroup = l>>4 (16 d's each).
__global__ __launch_bounds__(256) void attn_kernel(const unsigned short* __restrict__ QKV,
                                                   const float* __restrict__ mask,
                                                   float* __restrict__ out) {
  __shared__ unsigned short sh[4][3072];
  const int wave = threadIdx.x >> 6;
  const int lane = threadIdx.x & 63;
  const int pos = blockIdx.x * 4 + wave;

  const unsigned short* row = QKV + (size_t)pos * 3072;
  // stage 3072 bf16 = 384 x ushort8
  #pragma unroll
  for (int c = 0; c < 6; ++c) {
    int idx = (c * 64 + lane) * 8;
    *(bf16x8*)&sh[wave][idx] = *(const bf16x8*)&row[idx];
  }
  __syncthreads();

  const int h = lane & 15;
  const int dg = lane >> 4;

  float q[64];
  #pragma unroll
  for (int d = 0; d < 64; ++d) q[d] = bf2f(sh[wave][h * 64 + d]);

  const float* mrow = mask + (size_t)pos * 256 + h * 16;
  float s[16];
  float mx = -1e30f;
  #pragma unroll
  for (int g = 0; g < 16; ++g) {
    float acc = 0.f;
    #pragma unroll
    for (int d = 0; d < 64; ++d)
      acc += q[d] * bf2f(sh[wave][1024 + g * 64 + d]);
    acc = acc * 0.125f + mrow[g];
    s[g] = acc;
    mx = fmaxf(mx, acc);
  }
  float sum = 0.f;
  #pragma unroll
  for (int g = 0; g < 16; ++g) { s[g] = __expf(s[g] - mx); sum += s[g]; }
  float inv = 1.f / sum;

  float o[16];
  #pragma unroll
  for (int dd = 0; dd < 16; ++dd) o[dd] = 0.f;
  #pragma unroll
  for (int g = 0; g < 16; ++g) {
    float p = s[g];
    #pragma unroll
    for (int dd = 0; dd < 16; ++dd)
      o[dd] += p * bf2f(sh[wave][2048 + g * 64 + dg * 16 + dd]);
  }
  float* orow = out + (size_t)pos * 1024 + h * 64 + dg * 16;
  #pragma unroll
  for (int dd = 0; dd < 16; ++dd) orow[dd] = o[dd] * inv;
}

extern "C" void kernel_launch(void* const* d_in, const int* in_sizes, int n_in,
                              void* d_out, int out_size, void* d_ws, size_t ws_size,
                              hipStream_t stream) {
  const float* query = (const float*)d_in[0];
  // d_in[1] (key) and d_in[2] (value) are unused by the reference.
  const float* mask  = (const float*)d_in[3];
  const float* Wqkv  = (const float*)d_in[4];
  const float* bqkv  = (const float*)d_in[5];
  float* out = (float*)d_out;

  unsigned short* qb   = (unsigned short*)d_ws;                                  // 16,777,216 el
  unsigned short* wb   = (unsigned short*)((char*)d_ws + 33554432);              //  3,145,728 el
  unsigned short* qkvb = (unsigned short*)((char*)d_ws + 39845888);              // 50,331,648 el

  cast_kernel<<<16384, 256, 0, stream>>>(query, qb, 16777216);
  cast_kernel<<<3072, 256, 0, stream>>>(Wqkv, wb, 3145728);

  dim3 g(128, 24);
  gemm_qkv<<<g, 256, 0, stream>>>(qb, wb, bqkv, qkvb);

  attn_kernel<<<4096, 256, 0, stream>>>(qkvb, mask, out);
}

// Round 2
// 383.587 us; speedup vs baseline: 1.1971x; 1.1971x over previous
//
#include <hip/hip_runtime.h>
#include <cstdint>
#include <cstddef>

// Problem: B=4, S=4096, HID=1024, H=16, DH=64
//   qkv = query @ W^T + b    (M=16384, N=3072, K=1024)
//   per-position (b,s): scores = q(16x64) @ k^T /8 + mask(16x16); softmax; o = p @ v(16x64)
// Pipeline: cast fp32->bf16 (query, W) -> MFMA GEMM (bf16, fp32 acc, +bias, store bf16)
//           -> per-position attention (fp32 in LDS) -> out fp32.
// ws layout: Qb bf16 [16M el] @0 ; Wb bf16 [3M el] @33554432 ; QKVb bf16 [48M el] @39845888

typedef __attribute__((ext_vector_type(8))) short bf16x8;
typedef __attribute__((ext_vector_type(4))) float f32x4;

__device__ inline unsigned short f2bf(float f) {
  unsigned int i = __float_as_uint(f);
  i += 0x7fff + ((i >> 16) & 1);   // RNE
  return (unsigned short)(i >> 16);
}

__device__ inline void async16(const void* g, void* l) {
  __builtin_amdgcn_global_load_lds(
      (const __attribute__((address_space(1))) void*)g,
      (__attribute__((address_space(3))) void*)l, 16, 0, 0);
}

// ---------------- cast fp32 -> bf16, 4 elems/thread ----------------
__global__ __launch_bounds__(256) void cast_kernel(const float* __restrict__ in,
                                                   unsigned short* __restrict__ out,
                                                   int n) {
  int i = (blockIdx.x * 256 + threadIdx.x) * 4;
  if (i >= n) return;
  float4 v = *(const float4*)(in + i);
  union { unsigned short u[4]; unsigned long long ll; } o;
  o.u[0] = f2bf(v.x); o.u[1] = f2bf(v.y); o.u[2] = f2bf(v.z); o.u[3] = f2bf(v.w);
  *(unsigned long long*)(out + i) = o.ll;
}

// ---------------- GEMM: C[M=16384][N=3072] = A[M][1024] * B[N][1024]^T + bias ----------------
// 128x128 tile, BK=64, 256 threads (4 waves, 2x2 of 64x64), mfma 16x16x32 bf16.
#define GK 1024
#define GN 3072
__global__ __launch_bounds__(256) void gemm_qkv(const unsigned short* __restrict__ A,
                                                const unsigned short* __restrict__ Bm,
                                                const float* __restrict__ bias,
                                                unsigned short* __restrict__ C) {
  __shared__ unsigned short As[128 * 64];
  __shared__ unsigned short Bs[128 * 64];
  const int m0 = blockIdx.x * 128;
  const int n0 = blockIdx.y * 128;
  const int tid  = threadIdx.x;
  const int lane = tid & 63;
  const int wave = tid >> 6;
  const int wm = wave & 1, wn = wave >> 1;       // 2x2 waves, each 64x64
  const int fr = lane & 15;                      // m (A) / n (B) within 16
  const int fq = lane >> 4;                      // quad -> k offset fq*8

  f32x4 acc[4][4] = {};

  for (int k0 = 0; k0 < GK; k0 += 64) {
    // stage A,B tiles: 1024 16B-chunks each; wave-uniform LDS base + lane*16
    #pragma unroll
    for (int t = 0; t < 4; ++t) {
      int sbase = t * 256 + wave * 64;           // wave-uniform slot base
      int sl = sbase + lane;
      int r = sl >> 3;
      int c = (sl & 7) * 8;
      async16(&A[(size_t)(m0 + r) * GK + k0 + c], &As[sbase * 8]);
      async16(&Bm[(size_t)(n0 + r) * GK + k0 + c], &Bs[sbase * 8]);
    }
    __syncthreads();
    #pragma unroll
    for (int ks = 0; ks < 64; ks += 32) {
      bf16x8 af[4], bf[4];
      #pragma unroll
      for (int i = 0; i < 4; ++i) {
        int arow = wm * 64 + i * 16 + fr;
        af[i] = *(const bf16x8*)&As[arow * 64 + ks + fq * 8];
        int brow = wn * 64 + i * 16 + fr;
        bf[i] = *(const bf16x8*)&Bs[brow * 64 + ks + fq * 8];
      }
      #pragma unroll
      for (int i = 0; i < 4; ++i)
        #pragma unroll
        for (int j = 0; j < 4; ++j)
          acc[i][j] = __builtin_amdgcn_mfma_f32_16x16x32_bf16(af[i], bf[j], acc[i][j], 0, 0, 0);
    }
    __syncthreads();
  }

  // epilogue: C[row][col] = acc + bias[col], store bf16
  #pragma unroll
  for (int i = 0; i < 4; ++i) {
    #pragma unroll
    for (int j = 0; j < 4; ++j) {
      int col = n0 + wn * 64 + j * 16 + fr;
      float bc = bias[col];
      #pragma unroll
      for (int r = 0; r < 4; ++r) {
        int row = m0 + wm * 64 + i * 16 + fq * 4 + r;
        C[(size_t)row * GN + col] = f2bf(acc[i][j][r] + bc);
      }
    }
  }
}

// ---------------- per-position attention ----------------
// one wave per position. lane = h*4 + dg  (h = lane>>2 in 0..15, dg = lane&3).
// Each lane owns d-slice [dg*16, dg*16+16): partial dots + 2-step butterfly reduce.
__global__ __launch_bounds__(256) void attn_kernel(const unsigned short* __restrict__ QKV,
                                                   const float* __restrict__ mask,
                                                   float* __restrict__ out) {
  __shared__ float sh[4][3072];
  const int wave = threadIdx.x >> 6;
  const int lane = threadIdx.x & 63;
  const int pos = blockIdx.x * 4 + wave;

  // ---- stage qkv row (3072 bf16) into LDS as fp32 ----
  const unsigned short* row = QKV + (size_t)pos * 3072;
  #pragma unroll
  for (int c = 0; c < 12; ++c) {
    int idx = c * 256 + lane * 4;                      // 4 elems per lane per chunk
    uint2 u = *(const uint2*)&row[idx];                // 4 packed bf16
    float4 f;
    f.x = __uint_as_float(u.x << 16);
    f.y = __uint_as_float(u.x & 0xffff0000u);
    f.z = __uint_as_float(u.y << 16);
    f.w = __uint_as_float(u.y & 0xffff0000u);
    *(float4*)&sh[wave][idx] = f;                      // lane-contiguous: conflict-free
  }
  __syncthreads();

  const int h = lane >> 2;
  const int dg = lane & 3;

  // q slice: q[h][dg*16 .. +16) = sh[lane*16 .. +16)
  float q[16];
  #pragma unroll
  for (int t = 0; t < 4; ++t)
    *(float4*)&q[t * 4] = *(const float4*)&sh[wave][lane * 16 + t * 4];

  // partial scores over this lane's 16 d's
  float s[16];
  #pragma unroll
  for (int g = 0; g < 16; ++g) {
    const float* kp = &sh[wave][1024 + g * 64 + dg * 16];
    float acc = 0.f;
    #pragma unroll
    for (int d = 0; d < 16; ++d) acc += q[d] * kp[d];
    s[g] = acc;
  }
  // reduce across the 4 dg lanes (xor 1, xor 2)
  #pragma unroll
  for (int g = 0; g < 16; ++g) {
    s[g] += __shfl_xor(s[g], 1);
    s[g] += __shfl_xor(s[g], 2);
  }

  // scale + mask + softmax (duplicated across dg lanes; cheap)
  const float* mrow = mask + (size_t)pos * 256 + h * 16;
  float mx = -1e30f;
  #pragma unroll
  for (int g = 0; g < 16; ++g) {
    s[g] = s[g] * 0.125f + mrow[g];
    mx = fmaxf(mx, s[g]);
  }
  float sum = 0.f;
  #pragma unroll
  for (int g = 0; g < 16; ++g) { s[g] = __expf(s[g] - mx); sum += s[g]; }
  float inv = 1.f / sum;

  // o[h][dg*16+dd] = sum_g p[g] * v[g][dg*16+dd]
  float o[16];
  #pragma unroll
  for (int dd = 0; dd < 16; ++dd) o[dd] = 0.f;
  #pragma unroll
  for (int g = 0; g < 16; ++g) {
    float p = s[g];
    const float* vp = &sh[wave][2048 + g * 64 + dg * 16];
    #pragma unroll
    for (int dd = 0; dd < 16; ++dd) o[dd] += p * vp[dd];
  }

  // store: out[pos*1024 + lane*16 .. +16)  — fully coalesced
  float* op = out + (size_t)pos * 1024 + lane * 16;
  #pragma unroll
  for (int t = 0; t < 4; ++t) {
    float4 w;
    w.x = o[t * 4 + 0] * inv; w.y = o[t * 4 + 1] * inv;
    w.z = o[t * 4 + 2] * inv; w.w = o[t * 4 + 3] * inv;
    *(float4*)(op + t * 4) = w;
  }
}

extern "C" void kernel_launch(void* const* d_in, const int* in_sizes, int n_in,
                              void* d_out, int out_size, void* d_ws, size_t ws_size,
                              hipStream_t stream) {
  const float* query = (const float*)d_in[0];
  // d_in[1] (key) and d_in[2] (value) are unused by the reference.
  const float* mask  = (const float*)d_in[3];
  const float* Wqkv  = (const float*)d_in[4];
  const float* bqkv  = (const float*)d_in[5];
  float* out = (float*)d_out;

  unsigned short* qb   = (unsigned short*)d_ws;                                  // 16,777,216 el
  unsigned short* wb   = (unsigned short*)((char*)d_ws + 33554432);              //  3,145,728 el
  unsigned short* qkvb = (unsigned short*)((char*)d_ws + 39845888);              // 50,331,648 el

  cast_kernel<<<16384, 256, 0, stream>>>(query, qb, 16777216);
  cast_kernel<<<3072, 256, 0, stream>>>(Wqkv, wb, 3145728);

  dim3 g(128, 24);
  gemm_qkv<<<g, 256, 0, stream>>>(qb, wb, bqkv, qkvb);

  attn_kernel<<<4096, 256, 0, stream>>>(qkvb, mask, out);
}